// Round 2
// baseline (717.851 us; speedup 1.0000x reference)
//
#include <hip/hip_runtime.h>
#include <hip/hip_bf16.h>

// Problem constants (Seq2SeqLSTM): H=64, F=8, 4H=256 gates, T=512, P=64, B=1024
#define Hh 64
#define Ff 8
#define Gg 256
#define Tt 512
#define Pp 64
#define BATCH 1024
#define BB 2          // batch elements per block -> 512 blocks = 2 blocks/CU

typedef __hip_bfloat16 bf16;

__device__ __forceinline__ float bf2f(bf16 v) { return __bfloat162float(v); }
__device__ __forceinline__ float sigmoidf_(float x) { return 1.f / (1.f + __expf(-x)); }
__device__ __forceinline__ float tanhf_(float x) { return 1.f - 2.f / (__expf(2.f * x) + 1.f); }

// Runtime dtype sniffer. probe = enc_bih: 256 x uniform(-0.125, 0.125).
// Read first 128 slots as bf16: if buffer is bf16 all 128 have |v|<0.2;
// if buffer is fp32 only ~95 do (64 high halves + ~half of the random
// low-mantissa halves). Deterministic for a fixed dataset.
__device__ __forceinline__ bool detect_bf16(const void* probe) {
    const bf16* p = (const bf16*)probe;
    int cnt = 0;
    for (int i = 0; i < 128; ++i) {
        float v = bf2f(p[i]);
        if (fabsf(v) < 0.2f) ++cnt;   // NaN fails the compare -> not counted
    }
    return cnt >= 120;
}

// Generic boundary load: fp32 or bf16 per flag. Internal compute is fp32.
__device__ __forceinline__ float ldv(const void* p, size_t i, bool isbf) {
    return isbf ? bf2f(((const bf16*)p)[i]) : ((const float*)p)[i];
}

// One persistent block per BB batch elements. Thread t owns gate row g=t
// (rows 0..63 = i, 64..127 = f, 128..191 = g, 192..255 = o), with the 72
// weights for that row held in VGPRs. h/c live in LDS; per-step LDS reads of
// h are wave-uniform broadcasts (conflict-free).
__global__ __launch_bounds__(256, 2)
void seq2seq_lstm(const void* __restrict__ x_seq,
                  const void* __restrict__ eWih, const void* __restrict__ eWhh,
                  const void* __restrict__ ebih, const void* __restrict__ ebhh,
                  const void* __restrict__ dWih, const void* __restrict__ dWhh,
                  const void* __restrict__ dbih, const void* __restrict__ dbhh,
                  const void* __restrict__ fcW,  const void* __restrict__ fcb,
                  void* __restrict__ out)
{
    __shared__ float hs[BB][Hh];
    __shared__ float cs[BB][Hh];
    __shared__ float xs[BB][Ff];
    __shared__ float gates[BB][Gg];
    __shared__ float sfcW[Ff][Hh];
    __shared__ float sfcb[Ff];

    const int tid = threadIdx.x;
    const int g   = tid;                 // gate row
    const int b0  = blockIdx.x * BB;     // first batch element of this block

    const bool isbf = detect_bf16(ebih); // uniform across all threads/blocks

    // ---- encoder weights -> registers (73 fp32 values per thread)
    float wih[Ff], whh[Hh], bias;
    #pragma unroll
    for (int k = 0; k < Ff; ++k) wih[k] = ldv(eWih, g * Ff + k, isbf);
    #pragma unroll
    for (int j = 0; j < Hh; ++j) whh[j] = ldv(eWhh, g * Hh + j, isbf);
    bias = ldv(ebih, g, isbf) + ldv(ebhh, g, isbf);

    // ---- init LDS state, fc weights, x(t=0)
    if (tid < BB * Hh) { hs[tid / Hh][tid % Hh] = 0.f; cs[tid / Hh][tid % Hh] = 0.f; }
    {   // fcW: 8*64 = 512 elements, 2 per thread
        int i0 = tid * 2;
        ((float*)sfcW)[i0]     = ldv(fcW, i0, isbf);
        ((float*)sfcW)[i0 + 1] = ldv(fcW, i0 + 1, isbf);
    }
    if (tid < Ff) sfcb[tid] = ldv(fcb, tid, isbf);
    if (tid < BB * Ff) {
        int b = tid / Ff, k = tid % Ff;
        xs[b][k] = ldv(x_seq, (size_t)(b0 + b) * Tt * Ff + k, isbf);
    }
    __syncthreads();

    // ================= encoder: T sequential steps =================
    for (int t = 0; t < Tt; ++t) {
        // phase 1: each thread computes its gate pre-activation for BB elems
        #pragma unroll
        for (int b = 0; b < BB; ++b) {
            float a0 = bias, a1 = 0.f, a2 = 0.f, a3 = 0.f;
            #pragma unroll
            for (int k = 0; k < Ff; k += 4) {
                a0 += wih[k]     * xs[b][k];
                a1 += wih[k + 1] * xs[b][k + 1];
                a2 += wih[k + 2] * xs[b][k + 2];
                a3 += wih[k + 3] * xs[b][k + 3];
            }
            #pragma unroll
            for (int j = 0; j < Hh; j += 4) {
                a0 += whh[j]     * hs[b][j];
                a1 += whh[j + 1] * hs[b][j + 1];
                a2 += whh[j + 2] * hs[b][j + 2];
                a3 += whh[j + 3] * hs[b][j + 3];
            }
            gates[b][g] = (a0 + a1) + (a2 + a3);
        }
        __syncthreads();
        // phase 2: threads 0..127 update (h,c); threads 128..143 prefetch x(t+1)
        if (tid < BB * Hh) {
            int b = tid / Hh, u = tid % Hh;
            float ig = gates[b][u];
            float fg = gates[b][Hh + u];
            float gg = gates[b][2 * Hh + u];
            float og = gates[b][3 * Hh + u];
            float cn = sigmoidf_(fg) * cs[b][u] + sigmoidf_(ig) * tanhf_(gg);
            float hn = sigmoidf_(og) * tanhf_(cn);
            cs[b][u] = cn;
            hs[b][u] = hn;
        } else if (tid >= 128 && tid < 128 + BB * Ff) {
            if (t + 1 < Tt) {
                int q = tid - 128;
                int b = q / Ff, k = q % Ff;
                xs[b][k] = ldv(x_seq, (size_t)(b0 + b) * Tt * Ff + (size_t)(t + 1) * Ff + k, isbf);
            }
        }
        __syncthreads();
    }

    // ---- swap in decoder weights; x <- last input frame
    #pragma unroll
    for (int k = 0; k < Ff; ++k) wih[k] = ldv(dWih, g * Ff + k, isbf);
    #pragma unroll
    for (int j = 0; j < Hh; ++j) whh[j] = ldv(dWhh, g * Hh + j, isbf);
    bias = ldv(dbih, g, isbf) + ldv(dbhh, g, isbf);
    if (tid < BB * Ff) {
        int b = tid / Ff, k = tid % Ff;
        xs[b][k] = ldv(x_seq, (size_t)(b0 + b) * Tt * Ff + (size_t)(Tt - 1) * Ff + k, isbf);
    }
    __syncthreads();

    // ================= decoder: P steps with prediction feedback =================
    for (int p = 0; p < Pp; ++p) {
        #pragma unroll
        for (int b = 0; b < BB; ++b) {
            float a0 = bias, a1 = 0.f, a2 = 0.f, a3 = 0.f;
            #pragma unroll
            for (int k = 0; k < Ff; k += 4) {
                a0 += wih[k]     * xs[b][k];
                a1 += wih[k + 1] * xs[b][k + 1];
                a2 += wih[k + 2] * xs[b][k + 2];
                a3 += wih[k + 3] * xs[b][k + 3];
            }
            #pragma unroll
            for (int j = 0; j < Hh; j += 4) {
                a0 += whh[j]     * hs[b][j];
                a1 += whh[j + 1] * hs[b][j + 1];
                a2 += whh[j + 2] * hs[b][j + 2];
                a3 += whh[j + 3] * hs[b][j + 3];
            }
            gates[b][g] = (a0 + a1) + (a2 + a3);
        }
        __syncthreads();
        if (tid < BB * Hh) {
            int b = tid / Hh, u = tid % Hh;
            float ig = gates[b][u];
            float fg = gates[b][Hh + u];
            float gg = gates[b][2 * Hh + u];
            float og = gates[b][3 * Hh + u];
            float cn = sigmoidf_(fg) * cs[b][u] + sigmoidf_(ig) * tanhf_(gg);
            float hn = sigmoidf_(og) * tanhf_(cn);
            cs[b][u] = cn;
            hs[b][u] = hn;
        }
        __syncthreads();
        // fc head: pred = h @ fcW^T + fcb ; write out and feed back fp32
        if (tid < BB * Ff) {
            int b = tid / Ff, f = tid % Ff;
            float s0 = sfcb[f], s1 = 0.f, s2 = 0.f, s3 = 0.f;
            #pragma unroll
            for (int u = 0; u < Hh; u += 4) {
                s0 += sfcW[f][u]     * hs[b][u];
                s1 += sfcW[f][u + 1] * hs[b][u + 1];
                s2 += sfcW[f][u + 2] * hs[b][u + 2];
                s3 += sfcW[f][u + 3] * hs[b][u + 3];
            }
            float s = (s0 + s1) + (s2 + s3);
            size_t oi = (size_t)(b0 + b) * Pp * Ff + (size_t)p * Ff + f;
            if (isbf) ((bf16*)out)[oi] = __float2bfloat16(s);
            else      ((float*)out)[oi] = s;
            xs[b][f] = s;   // fp32 feedback, matching the reference scan carry
        }
        __syncthreads();
    }
}

extern "C" void kernel_launch(void* const* d_in, const int* in_sizes, int n_in,
                              void* d_out, int out_size, void* d_ws, size_t ws_size,
                              hipStream_t stream) {
    dim3 grid(BATCH / BB), block(256);
    hipLaunchKernelGGL(seq2seq_lstm, grid, block, 0, stream,
                       d_in[0], d_in[1], d_in[2], d_in[3], d_in[4],
                       d_in[5], d_in[6], d_in[7], d_in[8], d_in[9], d_in[10],
                       d_out);
}

// Round 3
// 717.564 us; speedup vs baseline: 1.0004x; 1.0004x over previous
//
#include <hip/hip_runtime.h>
#include <hip/hip_bf16.h>

// Seq2SeqLSTM: H=64, F=8, T=512, P=64, B=1024. fp32 in/out (verified R2).
// MFMA scheme: 64 blocks x 256 threads; 16 batches/block (= MFMA M dim).
// Wave w owns gate tiles {w, w+4, w+8, w+12} -> all 4 gate types for units
// u in [16w,16w+16) stay in-lane; c-state fp32 in VGPRs; h via LDS (bf16).
// Weights split hi+lo bf16 (2 MFMA chains) to kill systematic quant bias.

#define Hh 64
#define Ff 8
#define Tt 512
#define Pp 64
#define BATCH 1024
#define MB 16
#define NBLK (BATCH / MB)   // 64
#define ROWS 104            // shorts per LDS row: h(64) + x(8) + zeros(24) + pad(8)

typedef __attribute__((ext_vector_type(8))) short short8;
typedef __attribute__((ext_vector_type(4))) float f32x4;

__device__ __forceinline__ short f2bf(float x) {           // fp32 -> bf16 (RNE)
    unsigned u = __float_as_uint(x);
    u += 0x7fffu + ((u >> 16) & 1u);
    return (short)(u >> 16);
}
__device__ __forceinline__ float bf2f_s(short s) {
    return __uint_as_float(((unsigned)(unsigned short)s) << 16);
}
__device__ __forceinline__ float sigf(float x) {
    return __fdividef(1.f, 1.f + __expf(-x));
}
__device__ __forceinline__ float tanh_f(float x) {
    return 1.f - __fdividef(2.f, __expf(2.f * x) + 1.f);
}

// Load B-fragments (weights) for this lane: 4 gate tiles x 3 K-chunks, hi+lo split.
// B layout (16x16x32): lane holds B[k = kc*32 + quad*8 + j][n = lane&15].
// k 0..63 -> Whh[g][k]; k 64..71 -> Wih[g][k-64]; k 72..95 -> 0.
__device__ __forceinline__ void load_wfrags(
    const float* __restrict__ Whh, const float* __restrict__ Wih,
    int wv, int quad, int col, short8 whi[4][3], short8 wlo[4][3])
{
    #pragma unroll
    for (int Tg = 0; Tg < 4; ++Tg) {
        int g = Tg * 64 + wv * 16 + col;
        const float* r0 = Whh + g * 64 + quad * 8;
        const float* r1 = r0 + 32;
        #pragma unroll
        for (int j = 0; j < 8; ++j) {
            float v0 = r0[j];
            short h0 = f2bf(v0);
            whi[Tg][0][j] = h0;
            wlo[Tg][0][j] = f2bf(v0 - bf2f_s(h0));
            float v1 = r1[j];
            short h1 = f2bf(v1);
            whi[Tg][1][j] = h1;
            wlo[Tg][1][j] = f2bf(v1 - bf2f_s(h1));
            float v2 = (quad == 0) ? Wih[g * 8 + j] : 0.f;
            short h2 = f2bf(v2);
            whi[Tg][2][j] = h2;
            wlo[Tg][2][j] = f2bf(v2 - bf2f_s(h2));
        }
    }
}

// One LSTM step: 24 MFMA + in-register cell update; writes h (bf16) to nxt.
__device__ __forceinline__ void lstm_step(
    const short* __restrict__ cur, short* __restrict__ nxt,
    const short8 whi[4][3], const short8 wlo[4][3],
    const float bias[4], f32x4& cst, int quad, int col, int u)
{
    // A layout (16x16x32): lane holds A[m = lane&15][k = quad*8 + j]
    const short* arow = cur + col * ROWS;
    short8 a0 = *(const short8*)(arow + quad * 8);        // k  0..31
    short8 a1 = *(const short8*)(arow + 32 + quad * 8);   // k 32..63
    short8 a2 = *(const short8*)(arow + 64 + quad * 8);   // k 64..95 (x + zeros)

    f32x4 z = {0.f, 0.f, 0.f, 0.f};
    f32x4 acc[4];
    #pragma unroll
    for (int Tg = 0; Tg < 4; ++Tg)
        acc[Tg] = __builtin_amdgcn_mfma_f32_16x16x32_bf16(a0, whi[Tg][0], z, 0, 0, 0);
    #pragma unroll
    for (int Tg = 0; Tg < 4; ++Tg)
        acc[Tg] = __builtin_amdgcn_mfma_f32_16x16x32_bf16(a1, whi[Tg][1], acc[Tg], 0, 0, 0);
    #pragma unroll
    for (int Tg = 0; Tg < 4; ++Tg)
        acc[Tg] = __builtin_amdgcn_mfma_f32_16x16x32_bf16(a2, whi[Tg][2], acc[Tg], 0, 0, 0);
    #pragma unroll
    for (int Tg = 0; Tg < 4; ++Tg)
        acc[Tg] = __builtin_amdgcn_mfma_f32_16x16x32_bf16(a0, wlo[Tg][0], acc[Tg], 0, 0, 0);
    #pragma unroll
    for (int Tg = 0; Tg < 4; ++Tg)
        acc[Tg] = __builtin_amdgcn_mfma_f32_16x16x32_bf16(a1, wlo[Tg][1], acc[Tg], 0, 0, 0);
    #pragma unroll
    for (int Tg = 0; Tg < 4; ++Tg)
        acc[Tg] = __builtin_amdgcn_mfma_f32_16x16x32_bf16(a2, wlo[Tg][2], acc[Tg], 0, 0, 0);

    // Cell update. C/D layout: col = lane&15 (gate n), row m = quad*4 + r.
    #pragma unroll
    for (int r = 0; r < 4; ++r) {
        float iv = acc[0][r] + bias[0];
        float fv = acc[1][r] + bias[1];
        float gv = acc[2][r] + bias[2];
        float ov = acc[3][r] + bias[3];
        float cn = sigf(fv) * cst[r] + sigf(iv) * tanh_f(gv);
        float hn = sigf(ov) * tanh_f(cn);
        cst[r] = cn;
        nxt[(quad * 4 + r) * ROWS + u] = f2bf(hn);
    }
}

__global__ __launch_bounds__(256, 1)
void seq2seq_mfma(const float* __restrict__ x_seq,
                  const float* __restrict__ eWih, const float* __restrict__ eWhh,
                  const float* __restrict__ ebih, const float* __restrict__ ebhh,
                  const float* __restrict__ dWih, const float* __restrict__ dWhh,
                  const float* __restrict__ dbih, const float* __restrict__ dbhh,
                  const float* __restrict__ fcW,  const float* __restrict__ fcb,
                  float* __restrict__ out)
{
    __shared__ __align__(16) short Abuf[2][MB * ROWS];   // 6656 B
    __shared__ float fcWT[Hh * 9];                       // [u][f] stride 9: bank-spread
    __shared__ float sfcb[Ff];

    const int tid  = threadIdx.x;
    const int wv   = tid >> 6;
    const int lane = tid & 63;
    const int quad = lane >> 4;
    const int col  = lane & 15;
    const int u    = wv * 16 + col;      // unit owned by this lane's C columns
    const int b0   = blockIdx.x * MB;

    short8 whi[4][3], wlo[4][3];
    load_wfrags(eWhh, eWih, wv, quad, col, whi, wlo);
    float bias[4];
    #pragma unroll
    for (int Tg = 0; Tg < 4; ++Tg) { int g = Tg * 64 + u; bias[Tg] = ebih[g] + ebhh[g]; }

    // init LDS: zero both A buffers (h=0, x pad zeros), stage fc weights transposed
    { int* Z = (int*)Abuf; for (int i = tid; i < MB * ROWS; i += 256) Z[i] = 0; }
    for (int i = tid; i < Ff * Hh; i += 256) { int f = i >> 6, uu = i & 63; fcWT[uu * 9 + f] = fcW[i]; }
    if (tid < Ff) sfcb[tid] = fcb[tid];
    __syncthreads();

    // x(t=0) into buf0; prefetch x(t=1) into registers
    float xp[8];
    if (tid < MB) {
        const float* px = x_seq + ((size_t)(b0 + tid) * Tt) * Ff;
        short8 xb;
        #pragma unroll
        for (int j = 0; j < 8; ++j) xb[j] = f2bf(px[j]);
        *(short8*)(&Abuf[0][tid * ROWS + 64]) = xb;
        #pragma unroll
        for (int j = 0; j < 8; ++j) xp[j] = px[Ff + j];
    }
    __syncthreads();

    f32x4 cst = {0.f, 0.f, 0.f, 0.f};
    int curb = 0;

    // ===================== encoder: 512 steps, 1 barrier each =====================
    for (int t = 0; t < Tt; ++t) {
        const short* cur = Abuf[curb];
        short*       nxt = Abuf[curb ^ 1];
        lstm_step(cur, nxt, whi, wlo, bias, cst, quad, col, u);
        if (tid < MB) {   // write x(t+1) (held in regs) into nxt; prefetch x(t+2)
            short8 xb;
            #pragma unroll
            for (int j = 0; j < 8; ++j) xb[j] = f2bf(xp[j]);
            *(short8*)(nxt + tid * ROWS + 64) = xb;
            int tn = (t + 2 < Tt) ? (t + 2) : (Tt - 1);
            const float* px = x_seq + ((size_t)(b0 + tid) * Tt + tn) * Ff;
            #pragma unroll
            for (int j = 0; j < 8; ++j) xp[j] = px[j];
        }
        __syncthreads();
        curb ^= 1;
    }

    // ===================== decoder: 64 steps, fc + feedback =====================
    load_wfrags(dWhh, dWih, wv, quad, col, whi, wlo);
    #pragma unroll
    for (int Tg = 0; Tg < 4; ++Tg) { int g = Tg * 64 + u; bias[Tg] = dbih[g] + dbhh[g]; }

    for (int p = 0; p < Pp; ++p) {
        const short* cur = Abuf[curb];
        short*       nxt = Abuf[curb ^ 1];
        lstm_step(cur, nxt, whi, wlo, bias, cst, quad, col, u);
        __syncthreads();
        // fc head: pred = h_new @ fcW^T + fcb; write out (fp32) + feed back as x
        if (tid < MB * Ff) {
            int b = tid >> 3, f = tid & 7;
            const short* hr = nxt + b * ROWS;
            float s = sfcb[f];
            #pragma unroll
            for (int ch = 0; ch < 8; ++ch) {
                short8 hh = *(const short8*)(hr + ch * 8);
                #pragma unroll
                for (int j = 0; j < 8; ++j)
                    s += bf2f_s(hh[j]) * fcWT[(ch * 8 + j) * 9 + f];
            }
            out[((size_t)(b0 + b) * Pp + p) * Ff + f] = s;
            nxt[b * ROWS + 64 + f] = f2bf(s);
        }
        __syncthreads();
        curb ^= 1;
    }
}

extern "C" void kernel_launch(void* const* d_in, const int* in_sizes, int n_in,
                              void* d_out, int out_size, void* d_ws, size_t ws_size,
                              hipStream_t stream) {
    (void)in_sizes; (void)n_in; (void)d_ws; (void)ws_size; (void)out_size;
    hipLaunchKernelGGL(seq2seq_mfma, dim3(NBLK), dim3(256), 0, stream,
                       (const float*)d_in[0],
                       (const float*)d_in[1], (const float*)d_in[2],
                       (const float*)d_in[3], (const float*)d_in[4],
                       (const float*)d_in[5], (const float*)d_in[6],
                       (const float*)d_in[7], (const float*)d_in[8],
                       (const float*)d_in[9], (const float*)d_in[10],
                       (float*)d_out);
}